// Round 1
// baseline (2057.811 us; speedup 1.0000x reference)
//
#include <hip/hip_runtime.h>

// Problem constants
#define B_    4
#define T_    1024
#define E_    512
#define Hh    8
#define L_    4
#define V_    32000
#define HID_  100
#define HIDP  128
#define BT    4096   // B_*T_

typedef float f32x4 __attribute__((ext_vector_type(4)));
typedef short s16x8 __attribute__((ext_vector_type(8)));

__device__ __forceinline__ short f2bf(float f) {
  unsigned u = __float_as_uint(f);
  u += 0x7fff + ((u >> 16) & 1);   // RNE to bf16
  return (short)(u >> 16);
}

__device__ __forceinline__ s16x8 cvt8(float4 a, float4 b) {
  s16x8 s;
  s[0] = f2bf(a.x); s[1] = f2bf(a.y); s[2] = f2bf(a.z); s[3] = f2bf(a.w);
  s[4] = f2bf(b.x); s[5] = f2bf(b.y); s[6] = f2bf(b.z); s[7] = f2bf(b.w);
  return s;
}

// async global->LDS, 16B per lane; LDS dest is wave-uniform base + lane*16
#define GLD16(g, l) __builtin_amdgcn_global_load_lds(                          \
    (const __attribute__((address_space(1))) void*)(g),                        \
    (__attribute__((address_space(3))) void*)(l), 16, 0, 0)

// ---------------------------------------------------------------------------
// Fast bf16 GEMM (m97 structure): C[M,N] = A[M,K] x Bt[N,K]^T (+bias)(+relu)
// A, Bt are bf16 with K contiguous (lda=ldb=K). 128x128 tile, BK=32,
// 256 threads = 4 waves, each wave owns a 64x64 quadrant (4x4 16x16 frags).
// Staging via global_load_lds width-16 into linear LDS [row][32k].
// ---------------------------------------------------------------------------
template<bool BIAS, bool RELU, bool RESID, bool OUTBF16>
__global__ __launch_bounds__(256) void bgemm_k(
    const short* __restrict__ A, const short* __restrict__ Bt,
    void* __restrict__ Cv, const float* __restrict__ bias,
    int K, int ldc)
{
  const int bm = blockIdx.y << 7;
  const int bn = blockIdx.x << 7;

  __shared__ __attribute__((aligned(16))) short As[128 * 32];
  __shared__ __attribute__((aligned(16))) short Bs[128 * 32];

  const int tid  = threadIdx.x;
  const int lane = tid & 63, w = tid >> 6;
  const int quad = lane >> 4, l15 = lane & 15;
  const int wm = (w >> 1) << 6, wn = (w & 1) << 6;

  f32x4 acc[4][4];
#pragma unroll
  for (int m = 0; m < 4; m++)
#pragma unroll
    for (int n = 0; n < 4; n++) acc[m][n] = (f32x4){0.f, 0.f, 0.f, 0.f};

  // staging: thread t covers row t>>2 (0..63), 16B chunk (t&3) of the 64B row
  const int srow = tid >> 2, scol = (tid & 3) << 3;
  const short* ga = A  + (long)(bm + srow) * K + scol;
  const short* gb = Bt + (long)(bn + srow) * K + scol;
  short* la = As + (w << 9);   // wave-uniform LDS base (w*1024 bytes)
  short* lb = Bs + (w << 9);

  for (int k0 = 0; k0 < K; k0 += 32) {
    GLD16(ga,                 la);          // A rows 0..63
    GLD16(ga + (long)64 * K,  la + 2048);   // A rows 64..127
    GLD16(gb,                 lb);
    GLD16(gb + (long)64 * K,  lb + 2048);
    ga += 32; gb += 32;
    __syncthreads();

    s16x8 af[4], bfr[4];
#pragma unroll
    for (int m = 0; m < 4; m++)
      af[m] = *(const s16x8*)&As[(wm + m * 16 + l15) * 32 + (quad << 3)];
#pragma unroll
    for (int n = 0; n < 4; n++)
      bfr[n] = *(const s16x8*)&Bs[(wn + n * 16 + l15) * 32 + (quad << 3)];
#pragma unroll
    for (int m = 0; m < 4; m++)
#pragma unroll
      for (int n = 0; n < 4; n++)
        acc[m][n] = __builtin_amdgcn_mfma_f32_16x16x32_bf16(af[m], bfr[n], acc[m][n], 0, 0, 0);
    __syncthreads();
  }

  // C/D layout: col = lane&15, row = quad*4 + reg  [verified m89/m91]
#pragma unroll
  for (int m = 0; m < 4; m++) {
#pragma unroll
    for (int n = 0; n < 4; n++) {
#pragma unroll
      for (int r = 0; r < 4; r++) {
        int gr = bm + wm + m * 16 + quad * 4 + r;
        int gc = bn + wn + n * 16 + l15;
        long ci = (long)gr * ldc + gc;
        float val = acc[m][n][r];
        if (BIAS) val += bias[gc];
        if (RELU) val = fmaxf(val, 0.f);
        if (OUTBF16) {
          ((short*)Cv)[ci] = f2bf(val);
        } else {
          float* Cf = (float*)Cv;
          if (RESID) val += Cf[ci];
          Cf[ci] = val;
        }
      }
    }
  }
}

// ---------------------------------------------------------------------------
// Legacy fp32-input GEMM (kept for the strided attention GEMMs):
// C = op(A[M,K] x B) * scale (+bias)(+relu)(+resid). TRANSB: B is (N,K).
// Batched over z -> (bz,hz). 64x64 tile, BK=32.
// ---------------------------------------------------------------------------
template<bool TRANSB, bool BIAS, bool RELU, bool RESID, bool OUTBF16>
__global__ __launch_bounds__(256) void gemm_k(
    const float* __restrict__ A, const float* __restrict__ B,
    void* __restrict__ Cv, const float* __restrict__ bias,
    int M, int N, int K, int lda, int ldb, int ldc,
    long sAb, long sAh, long sBb, long sBh, long sCb, long sCh,
    int Hn, float scale)
{
  const int z  = blockIdx.z;
  const int bz = z / Hn, hz = z - bz * Hn;
  A += bz * sAb + hz * sAh;
  B += bz * sBb + hz * sBh;
  const long coff = bz * sCb + hz * sCh;

  const int bm = blockIdx.y << 6;
  const int bn = blockIdx.x << 6;

  __shared__ short As[64 * 40];
  __shared__ short Bs[64 * 40];

  const int tid  = threadIdx.x;
  const int lane = tid & 63, w = tid >> 6;
  const int quad = lane >> 4, l15 = lane & 15;

  f32x4 acc[4];
#pragma unroll
  for (int i = 0; i < 4; i++) acc[i] = (f32x4){0.f, 0.f, 0.f, 0.f};

  const int arow = tid >> 2;
  const int acg  = (tid & 3) << 3;
  const int bkk  = tid >> 3;
  const int bng  = (tid & 7) << 3;

  for (int k0 = 0; k0 < K; k0 += 32) {
    {
      const float* ap = A + (long)(bm + arow) * lda + (k0 + acg);
      float4 u0 = *(const float4*)ap;
      float4 u1 = *(const float4*)(ap + 4);
      *(s16x8*)&As[arow * 40 + acg] = cvt8(u0, u1);
    }
    if (TRANSB) {
      const float* bp = B + (long)(bn + arow) * ldb + (k0 + acg);
      float4 u0 = *(const float4*)bp;
      float4 u1 = *(const float4*)(bp + 4);
      *(s16x8*)&Bs[arow * 40 + acg] = cvt8(u0, u1);
    } else {
      const float* bp = B + (long)(k0 + bkk) * ldb + (bn + bng);
      float4 u0 = *(const float4*)bp;
      float4 u1 = *(const float4*)(bp + 4);
      float vv[8] = {u0.x, u0.y, u0.z, u0.w, u1.x, u1.y, u1.z, u1.w};
#pragma unroll
      for (int j = 0; j < 8; j++) Bs[(bng + j) * 40 + bkk] = f2bf(vv[j]);
    }
    __syncthreads();

    s16x8 af = *(const s16x8*)&As[(w * 16 + l15) * 40 + (quad << 3)];
#pragma unroll
    for (int nt = 0; nt < 4; nt++) {
      s16x8 bf = *(const s16x8*)&Bs[(nt * 16 + l15) * 40 + (quad << 3)];
      acc[nt] = __builtin_amdgcn_mfma_f32_16x16x32_bf16(af, bf, acc[nt], 0, 0, 0);
    }
    __syncthreads();
  }

#pragma unroll
  for (int nt = 0; nt < 4; nt++) {
#pragma unroll
    for (int r = 0; r < 4; r++) {
      int gr = bm + w * 16 + quad * 4 + r;
      int gc = bn + nt * 16 + l15;
      long ci = coff + (long)gr * ldc + gc;
      float val = acc[nt][r] * scale;
      if (BIAS) val += bias[gc];
      if (RELU) val = fmaxf(val, 0.f);
      if (OUTBF16) {
        ((short*)Cv)[ci] = f2bf(val);
      } else {
        float* Cf = (float*)Cv;
        if (RESID) val += Cf[ci];
        Cf[ci] = val;
      }
    }
  }
}

// ---------------------------------------------------------------------------
// Tiled transpose-convert: in f32 (K,N) -> out bf16 (N,K). Batched in z.
// ---------------------------------------------------------------------------
__global__ __launch_bounds__(256) void tconv_k(
    const float* __restrict__ in, short* __restrict__ out,
    int K, int N, long sIn, long sOut)
{
  in  += (long)blockIdx.z * sIn;
  out += (long)blockIdx.z * sOut;
  __shared__ float t[32][33];
  int n0 = blockIdx.x << 5, k0 = blockIdx.y << 5;
  int tx = threadIdx.x, ty = threadIdx.y;
#pragma unroll
  for (int j = 0; j < 4; j++)
    t[ty + j * 8][tx] = in[(long)(k0 + ty + j * 8) * N + (n0 + tx)];
  __syncthreads();
#pragma unroll
  for (int j = 0; j < 4; j++)
    out[(long)(n0 + ty + j * 8) * K + (k0 + tx)] = f2bf(t[tx][ty + j * 8]);
}

// W1 (L,E,HID) f32 -> W1t (L,HIDP,E) bf16 (transposed, zero-padded); b1 -> b1p
__global__ __launch_bounds__(256) void padw1t_k(
    const float* __restrict__ W1, const float* __restrict__ b1,
    short* __restrict__ W1t, float* __restrict__ b1p)
{
  int i = blockIdx.x * 256 + threadIdx.x;   // L*HIDP*E = 262144
  int k = i & 511, n = (i >> 9) & 127, l = i >> 16;
  W1t[i] = (n < HID_) ? f2bf(W1[((long)(l * E_ + k)) * HID_ + n]) : (short)0;
  if (i < L_ * HIDP) {
    int nn = i & 127, ll = i >> 7;
    b1p[i] = (nn < HID_) ? b1[ll * HID_ + nn] : 0.f;
  }
}

// W2 (L,HID,E) f32 -> W2t (L,E,HIDP) bf16 (transposed, zero-padded)
__global__ __launch_bounds__(256) void padw2t_k(
    const float* __restrict__ W2, short* __restrict__ W2t)
{
  int i = blockIdx.x * 256 + threadIdx.x;   // L*E*HIDP = 262144
  int j = i & 127, n = (i >> 7) & 511, l = i >> 16;
  W2t[i] = (j < HID_) ? f2bf(W2[((long)(l * HID_ + j)) * E_ + n]) : (short)0;
}

// ---------------------------------------------------------------------------
// x[bt][e] = tok_emb[idx[bt]][e] + pos_emb[t][e]
// ---------------------------------------------------------------------------
__global__ __launch_bounds__(256) void embed_k(
    const int* __restrict__ idx, const float4* __restrict__ tok,
    const float4* __restrict__ pos, float4* __restrict__ x)
{
  int i = blockIdx.x * 256 + threadIdx.x;
  int bt = i >> 7, e4 = i & 127;
  int t = bt & (T_ - 1);
  int token = idx[bt];
  float4 a = tok[(long)token * 128 + e4];
  float4 p = pos[(long)t * 128 + e4];
  x[i] = make_float4(a.x + p.x, a.y + p.y, a.z + p.z, a.w + p.w);
}

// ---------------------------------------------------------------------------
// LayerNorm: one block per row of 512, bf16 output (feeds bf16 GEMM A)
// ---------------------------------------------------------------------------
__global__ __launch_bounds__(256) void ln_k(
    const float* __restrict__ x, const float* __restrict__ g,
    const float* __restrict__ b, short* __restrict__ out)
{
  int row = blockIdx.x;
  const float* xr = x + (long)row * E_;
  int tid = threadIdx.x;
  float v0 = xr[tid], v1 = xr[tid + 256];
  float s = v0 + v1, ss = v0 * v0 + v1 * v1;
#pragma unroll
  for (int off = 32; off; off >>= 1) {
    s  += __shfl_down(s, off);
    ss += __shfl_down(ss, off);
  }
  __shared__ float red[8];
  int w = tid >> 6, lane = tid & 63;
  if (lane == 0) { red[w] = s; red[w + 4] = ss; }
  __syncthreads();
  if (tid == 0) {
    float S  = red[0] + red[1] + red[2] + red[3];
    float SS = red[4] + red[5] + red[6] + red[7];
    float m  = S * (1.f / E_);
    float var = SS * (1.f / E_) - m * m;
    red[0] = m; red[1] = rsqrtf(var + 1e-5f);
  }
  __syncthreads();
  float m = red[0], r = red[1];
  short* orow = out + (long)row * E_;
  orow[tid]       = f2bf((v0 - m) * r * g[tid] + b[tid]);
  orow[tid + 256] = f2bf((v1 - m) * r * g[tid + 256] + b[tid + 256]);
}

// ---------------------------------------------------------------------------
// Causal softmax in place on (B*H*T) rows of length T. One wave per row.
// ---------------------------------------------------------------------------
__global__ __launch_bounds__(256) void softmax_k(float* __restrict__ S)
{
  int w = threadIdx.x >> 6, lane = threadIdx.x & 63;
  long rid = (long)blockIdx.x * 4 + w;
  float* row = S + rid * (long)T_;
  int t = (int)(rid & (T_ - 1));
  float e[16];
  float mx = -3.4e38f;
#pragma unroll
  for (int i = 0; i < 16; i++) {
    int j = lane + i * 64;
    float v = (j <= t) ? row[j] : -3.4e38f;
    e[i] = v;
    mx = fmaxf(mx, v);
  }
#pragma unroll
  for (int off = 32; off; off >>= 1) mx = fmaxf(mx, __shfl_xor(mx, off));
  float sum = 0.f;
#pragma unroll
  for (int i = 0; i < 16; i++) {
    int j = lane + i * 64;
    float v = (j <= t) ? __expf(e[i] - mx) : 0.f;
    e[i] = v; sum += v;
  }
#pragma unroll
  for (int off = 32; off; off >>= 1) sum += __shfl_xor(sum, off);
  float inv = 1.f / sum;
#pragma unroll
  for (int i = 0; i < 16; i++) row[lane + i * 64] = e[i] * inv;
}

// ---------------------------------------------------------------------------
extern "C" void kernel_launch(void* const* d_in, const int* in_sizes, int n_in,
                              void* d_out, int out_size, void* d_ws, size_t ws_size,
                              hipStream_t stream)
{
  const int*   idx  = (const int*)  d_in[0];
  const float* tok  = (const float*)d_in[1];
  const float* pos  = (const float*)d_in[2];
  const float* ln1g = (const float*)d_in[3];
  const float* ln1b = (const float*)d_in[4];
  const float* Wq   = (const float*)d_in[5];
  const float* Wk   = (const float*)d_in[6];
  const float* Wv   = (const float*)d_in[7];
  const float* Wo   = (const float*)d_in[8];
  const float* bo   = (const float*)d_in[9];
  const float* ln2g = (const float*)d_in[10];
  const float* ln2b = (const float*)d_in[11];
  const float* W1   = (const float*)d_in[12];
  const float* b1   = (const float*)d_in[13];
  const float* W2   = (const float*)d_in[14];
  const float* b2   = (const float*)d_in[15];
  const float* lnfg = (const float*)d_in[16];
  const float* lnfb = (const float*)d_in[17];
  const float* Wlm  = (const float*)d_in[18];

  float* out = (float*)d_out;

  // Workspace layout (52,430,848 bytes total; fits prior footprint):
  char*  wsb  = (char*)d_ws;
  float* x    = (float*)(wsb);               // BT*E f32        8,388,608
  float* qkv  = (float*)(wsb +  8388608);    // BT*1536 f32    25,165,824
  short* y    = (short*)(wsb + 33554432);    // BT*E bf16       4,194,304
  short* h    = (short*)(wsb + 37748736);    // BT*E bf16       4,194,304
  short* h2   = (short*)(wsb + 41943040);    // BT*HIDP bf16    1,048,576
  short* Wqkvt= (short*)(wsb + 42991616);    // L*1536*512 bf16 6,291,456
  short* Wot  = (short*)(wsb + 49283072);    // L*512*512 bf16  2,097,152
  short* W1t  = (short*)(wsb + 51380224);    // L*128*512 bf16    524,288
  short* W2t  = (short*)(wsb + 51904512);    // L*512*128 bf16    524,288
  float* b1p  = (float*)(wsb + 52428800);    // L*128 f32           2,048
  short* Wlmt = (short*)(wsb);               // 32000*512 bf16 = 32.77MB,
                                             // aliases x+qkv AFTER final LN

  float* attn0 = out + (long)BT * V_;
  const long TT = (long)T_ * T_;

  dim3 tb(32, 8);
  // Per-call weight transpose/convert to bf16 (N,K) — d_ws is poisoned each call
  tconv_k<<<dim3(16, 16, L_), tb, 0, stream>>>(Wq, Wqkvt,              512, 512, (long)E_ * E_, (long)1536 * 512);
  tconv_k<<<dim3(16, 16, L_), tb, 0, stream>>>(Wk, Wqkvt +  512 * 512, 512, 512, (long)E_ * E_, (long)1536 * 512);
  tconv_k<<<dim3(16, 16, L_), tb, 0, stream>>>(Wv, Wqkvt + 1024 * 512, 512, 512, (long)E_ * E_, (long)1536 * 512);
  tconv_k<<<dim3(16, 16, L_), tb, 0, stream>>>(Wo, Wot,                512, 512, (long)E_ * E_, (long)512 * 512);
  padw1t_k<<<dim3(1024), dim3(256), 0, stream>>>(W1, b1, W1t, b1p);
  padw2t_k<<<dim3(1024), dim3(256), 0, stream>>>(W2, W2t);

  embed_k<<<dim3(BT * E_ / 4 / 256), dim3(256), 0, stream>>>(
      idx, (const float4*)tok, (const float4*)pos, (float4*)x);

  for (int l = 0; l < L_; l++) {
    float* attnL = attn0 + (long)l * B_ * Hh * TT;

    ln_k<<<dim3(BT), dim3(256), 0, stream>>>(x, ln1g + l * E_, ln1b + l * E_, h);

    // fused qkv = h @ [Wq|Wk|Wv]  (4096x1536x512, bf16 fast path)
    bgemm_k<false,false,false,false><<<dim3(12, 32), dim3(256), 0, stream>>>(
        h, Wqkvt + (long)l * 1536 * 512, qkv, nullptr, 512, 1536);

    // scores = (q @ k^T) / 8  into attn region (raw, pre-softmax)
    gemm_k<true,false,false,false,false><<<dim3(16, 16, 32), dim3(256), 0, stream>>>(
        qkv, qkv + 512, attnL, nullptr,
        T_, T_, 64, 1536, 1536, T_,
        (long)T_ * 1536, 64, (long)T_ * 1536, 64, (long)Hh * TT, TT, Hh, 0.125f);

    softmax_k<<<dim3(B_ * Hh * T_ / 4), dim3(256), 0, stream>>>(attnL);

    // y = attn @ v  -> bf16 output (feeds bf16 Wo GEMM)
    gemm_k<false,false,false,false,true><<<dim3(1, 16, 32), dim3(256), 0, stream>>>(
        attnL, qkv + 1024, y, nullptr,
        T_, 64, T_, T_, 1536, E_,
        (long)Hh * TT, TT, (long)T_ * 1536, 64, (long)T_ * E_, 64, Hh, 1.f);

    // x += y @ Wo[l] + bo[l]
    bgemm_k<true,false,true,false><<<dim3(4, 32), dim3(256), 0, stream>>>(
        y, Wot + (long)l * E_ * E_, x, bo + l * E_, 512, 512);

    ln_k<<<dim3(BT), dim3(256), 0, stream>>>(x, ln2g + l * E_, ln2b + l * E_, h);

    // h2 = relu(h @ W1 + b1)  (bf16 out; pad cols 100..127 are exact zeros)
    bgemm_k<true,true,false,true><<<dim3(1, 32), dim3(256), 0, stream>>>(
        h, W1t + (long)l * HIDP * E_, h2, b1p + l * HIDP, 512, HIDP);

    // x += h2 @ W2 + b2  (K=128, pad rows multiply exact zeros)
    bgemm_k<true,false,true,false><<<dim3(4, 32), dim3(256), 0, stream>>>(
        h2, W2t + (long)l * E_ * HIDP, x, b2 + l * E_, HIDP, 512);
  }

  ln_k<<<dim3(BT), dim3(256), 0, stream>>>(x, lnfg, lnfb, h);

  // Wlm (512,32000) -> bf16 (32000,512) into the now-dead x/qkv region
  tconv_k<<<dim3(V_ / 32, 16, 1), tb, 0, stream>>>(Wlm, Wlmt, 512, V_, 0, 0);

  // logits = h @ Wlm  (4096x32000x512, the dominant GEMM)
  bgemm_k<false,false,false,false><<<dim3(V_ / 128, 32), dim3(256), 0, stream>>>(
      h, Wlmt, out, nullptr, 512, V_);
}